// Round 6
// baseline (987.676 us; speedup 1.0000x reference)
//
#include <hip/hip_runtime.h>
#include <hip/hip_bf16.h>
#include <cstdint>
#include <cstddef>

typedef __bf16 bf16;
typedef bf16 bf16x8 __attribute__((ext_vector_type(8)));
typedef float f32x4 __attribute__((ext_vector_type(4)));

#define N_TOK 196
#define DIM_ 384
#define HQKV 2304
#define NH 12
#define NPAD 224          // padded token count (m dim), 7*32
#define B_TOT 256

// ---------------------------------------------------------------- prep
__global__ __launch_bounds__(256) void prep_kernel(
    const float* __restrict__ qg, const float* __restrict__ qb,
    const float* __restrict__ qm, const float* __restrict__ qv,
    const float* __restrict__ pg, const float* __restrict__ pb,
    const float* __restrict__ pm, const float* __restrict__ pv,
    const float* __restrict__ abias, const int* __restrict__ idxs,
    float* __restrict__ sqkv, float* __restrict__ bqkv,
    float* __restrict__ sproj, float* __restrict__ bproj,
    float* __restrict__ abT)
{
    int i = blockIdx.x * 256 + threadIdx.x;
    if (i < HQKV) {
        float s = qg[i] * rsqrtf(qv[i] + 1e-5f);
        sqkv[i] = s;
        bqkv[i] = qb[i] - qm[i] * s;
    }
    if (i < DIM_) {
        float s = pg[i] * rsqrtf(pv[i] + 1e-5f);
        sproj[i] = s;
        bproj[i] = pb[i] - pm[i] * s;
    }
    // abT[h][m][q] = bias for key m, query q (transposed vs reference)
    if (i < NH * NPAD * NPAD) {
        int h = i / (NPAD * NPAD);
        int rem = i - h * (NPAD * NPAD);
        int m = rem / NPAD;
        int q = rem - m * NPAD;
        float v = -1e30f;
        if (m < N_TOK && q < N_TOK)
            v = abias[h * N_TOK + idxs[q * N_TOK + m]];
        abT[i] = v;
    }
}

// ---------------------------------------------------------------- f32 -> bf16 convert
__global__ __launch_bounds__(256) void convert_kernel(
    const float* __restrict__ src, bf16* __restrict__ dst, int n4)
{
    int stride = gridDim.x * 256;
    for (int i = blockIdx.x * 256 + threadIdx.x; i < n4; i += stride) {
        float4 v = ((const float4*)src)[i];
        bf16 o[4] = {(bf16)v.x, (bf16)v.y, (bf16)v.z, (bf16)v.w};
        *(uint2*)&dst[(size_t)i * 4] = *(uint2*)o;
    }
}

// ---------------------------------------------------------------- QKV GEMM (bf16 x bf16)
__global__ __launch_bounds__(256) void qkv_gemm(
    const bf16* __restrict__ x, const bf16* __restrict__ w,
    const float* __restrict__ sq, const float* __restrict__ bq,
    bf16* __restrict__ qkv_c)
{
    __shared__ bf16 As[128 * 40];
    __shared__ bf16 Bs[128 * 40];
    int t = threadIdx.x;
    int m0 = blockIdx.x * 128;
    int n0 = blockIdx.y * 128;
    int lane = t & 63, wid = t >> 6;
    int qr = (wid >> 1) * 64, qc = (wid & 1) * 64;
    int lr = lane & 15, lg = lane >> 4, lk = lg * 8;

    f32x4 acc[4][4];
#pragma unroll
    for (int fi = 0; fi < 4; ++fi)
#pragma unroll
        for (int fj = 0; fj < 4; ++fj)
            acc[fi][fj] = (f32x4){0.f, 0.f, 0.f, 0.f};

    int r = t >> 2, kk = (t & 3) * 8;
    for (int kt = 0; kt < DIM_ / 32; ++kt) {
        int k0 = kt * 32;
        {
            *(bf16x8*)&As[r * 40 + kk] =
                *(const bf16x8*)(x + (size_t)(m0 + r) * DIM_ + k0 + kk);
            *(bf16x8*)&As[(r + 64) * 40 + kk] =
                *(const bf16x8*)(x + (size_t)(m0 + r + 64) * DIM_ + k0 + kk);
            *(bf16x8*)&Bs[r * 40 + kk] =
                *(const bf16x8*)(w + (size_t)(n0 + r) * DIM_ + k0 + kk);
            *(bf16x8*)&Bs[(r + 64) * 40 + kk] =
                *(const bf16x8*)(w + (size_t)(n0 + r + 64) * DIM_ + k0 + kk);
        }
        __syncthreads();
        bf16x8 a[4], b[4];
#pragma unroll
        for (int f = 0; f < 4; ++f) {
            a[f] = *(bf16x8*)&As[(qr + f * 16 + lr) * 40 + lk];
            b[f] = *(bf16x8*)&Bs[(qc + f * 16 + lr) * 40 + lk];
        }
#pragma unroll
        for (int fi = 0; fi < 4; ++fi)
#pragma unroll
            for (int fj = 0; fj < 4; ++fj)
                acc[fi][fj] = __builtin_amdgcn_mfma_f32_16x16x32_bf16(a[fi], b[fj], acc[fi][fj], 0, 0, 0);
        __syncthreads();
    }

#pragma unroll
    for (int fj = 0; fj < 4; ++fj) {
        int col = n0 + qc + fj * 16 + lr;
        float s = sq[col], bb = bq[col];
        int h = col / 192, cc = col - h * 192;
#pragma unroll
        for (int fi = 0; fi < 4; ++fi) {
            int rb = m0 + qr + fi * 16 + lg * 4;
#pragma unroll
            for (int rr = 0; rr < 4; ++rr) {
                int row = rb + rr;
                int bl = row / N_TOK, n = row - bl * N_TOK;
                float v = acc[fi][fj][rr] * s + bb;
                qkv_c[((size_t)(bl * NH + h) * NPAD + n) * 192 + cc] = (bf16)v;
            }
        }
    }
}

// ---------------------------------------------------------------- attention
// qkv_c: [B*12][224][192] bf16 (cols 0:32 q, 32:64 k, 64:192 v)
// abT: [12][224][224] f32 (bias[m][q]), attn_c out: [B*196][1536] bf16
// S^T = K*Q^T per 16-q tile; P packed to bf16 fragments AT EXP TIME and
// 1/sum deferred to the PV epilogue (PV is linear) -> peak VGPR liveness
// fits the LDS-occupancy VGPR cap of 128 (R4 lesson: keeping S[14] f32
// live across PV spilled ~300MB/dispatch to scratch).
// R5 lesson: rs is per-lane for q = q0+lr (A-frag row), but acc's C-frag
// row is q = q0+lg*4+rr -> rs must be redistributed via __shfl before the
// epilogue or normalization uses the WRONG ROW's sum (absmax 3.7e-2).
__global__ __launch_bounds__(512) void attn_kernel(
    const bf16* __restrict__ qkv_c, const float* __restrict__ abT,
    bf16* __restrict__ attn_c)
{
    __shared__ bf16 k_s[224 * 40];
    __shared__ bf16 vT_s[128 * 224];   // [d][slot], XOR-swizzled
    int bh = blockIdx.x;
    int bl = bh / NH, h = bh - bl * NH;
    const bf16* base = qkv_c + (size_t)bh * NPAD * 192;
    int t = threadIdx.x;

    // stage K (rows >=196 zeroed)
    for (int c = t; c < 224 * 4; c += 512) {
        int r = c >> 2, g = c & 3;
        bf16x8 v;
        if (r < N_TOK) v = *(const bf16x8*)(base + (size_t)r * 192 + 32 + g * 8);
        else {
#pragma unroll
            for (int j = 0; j < 8; ++j) v[j] = (bf16)0.f;
        }
        *(bf16x8*)&k_s[r * 40 + g * 8] = v;
    }
    // stage V transposed: vT_s[d][slot(m)], slot permutation matches the
    // PV A-fragment k-order: slot = 32*blk + 8*g4 + 4*t16 + r4.
    for (int c = t; c < 56 * 16; c += 512) {
        int rp = c % 56, g = c / 56;
        int r0 = rp * 4;
        bf16x8 v[4];
#pragma unroll
        for (int i = 0; i < 4; ++i) {
            int rr = r0 + i;
            if (rr < N_TOK) v[i] = *(const bf16x8*)(base + (size_t)rr * 192 + 64 + g * 8);
            else {
#pragma unroll
                for (int j = 0; j < 8; ++j) v[i][j] = (bf16)0.f;
            }
        }
        int ml = r0 & 31, blk = r0 >> 5;
        int slot0 = blk * 32 + ((ml & 15) >> 2) * 8 + (ml >> 4) * 4 + (ml & 3);
#pragma unroll
        for (int j = 0; j < 8; ++j) {
            int d = g * 8 + j;
            bf16 w4[4] = {v[0][j], v[1][j], v[2][j], v[3][j]};
            int byte_off = (d * 448 + slot0 * 2) ^ ((d & 7) << 4);
            *(unsigned long long*)((char*)vT_s + byte_off) = *(unsigned long long*)w4;
        }
    }
    __syncthreads();

    int lane = t & 63, wid = t >> 6;
    int lr = lane & 15, lg = lane >> 4, lk = lg * 8;
    const float SCL = 0.17677669529663687f;  // 32^-0.5
    const float L2E = 1.4426950408889634f;
    const float* abh = abT + (size_t)h * NPAD * NPAD;
    int xorv = (lr & 7) << 4;

    for (int tile = wid; tile < 13; tile += 8) {
        int q0 = tile * 16;
        // Q fragment (B operand): lane holds q = q0+lr, k contig
        bf16x8 aq = *(const bf16x8*)(base + (size_t)(q0 + lr) * 192 + lk);
        // S^T tiles: D[m, q], lane holds q=lr, m = mt*16 + lg*4 + rr
        f32x4 S[14];
#pragma unroll
        for (int mt = 0; mt < 14; ++mt) {
            bf16x8 ak = *(const bf16x8*)&k_s[(mt * 16 + lr) * 40 + lk];
            f32x4 z = (f32x4){0.f, 0.f, 0.f, 0.f};
            S[mt] = __builtin_amdgcn_mfma_f32_16x16x32_bf16(ak, aq, z, 0, 0, 0);
        }
        int qc = q0 + lr; if (qc > N_TOK - 1) qc = N_TOK - 1;
        float mx = -1e30f;
#pragma unroll
        for (int mt = 0; mt < 14; ++mt)
#pragma unroll
            for (int rr = 0; rr < 4; ++rr) {
                int m = mt * 16 + lg * 4 + rr;
                float sv = S[mt][rr] * SCL + abh[(size_t)m * NPAD + qc];
                S[mt][rr] = sv;
                mx = fmaxf(mx, sv);
            }
        mx = fmaxf(mx, __shfl_xor(mx, 16, 64));
        mx = fmaxf(mx, __shfl_xor(mx, 32, 64));
        // exp + immediate bf16 pack (S dies here; 1/sum deferred to epilogue)
        bf16x8 pa[7];
        float sum = 0.f;
#pragma unroll
        for (int ks = 0; ks < 7; ++ks)
#pragma unroll
            for (int e = 0; e < 4; ++e) {
                float p0 = exp2f((S[2 * ks][e] - mx) * L2E);
                float p1 = exp2f((S[2 * ks + 1][e] - mx) * L2E);
                sum += p0 + p1;
                pa[ks][e] = (bf16)p0;
                pa[ks][e + 4] = (bf16)p1;
            }
        sum += __shfl_xor(sum, 16, 64);
        sum += __shfl_xor(sum, 32, 64);
        float rs = 1.f / sum;
        // Redistribute: this lane's acc rows are q = q0 + lg*4 + rr, whose
        // fully-reduced sum lives (identically) in lanes with lr == lg*4+rr;
        // source it from group 0 (lane index lg*4+rr).
        float rs_r[4];
#pragma unroll
        for (int rr = 0; rr < 4; ++rr)
            rs_r[rr] = __shfl(rs, lg * 4 + rr, 64);

        f32x4 acc[8];
#pragma unroll
        for (int dt = 0; dt < 8; ++dt) acc[dt] = (f32x4){0.f, 0.f, 0.f, 0.f};
#pragma unroll
        for (int ks = 0; ks < 7; ++ks)
#pragma unroll
            for (int dt = 0; dt < 8; ++dt) {
                int byte_off = ((dt * 16 + lr) * 448 + ks * 64 + lg * 16) ^ xorv;
                bf16x8 bv = *(const bf16x8*)((const char*)vT_s + byte_off);
                acc[dt] = __builtin_amdgcn_mfma_f32_16x16x32_bf16(pa[ks], bv, acc[dt], 0, 0, 0);
            }
        // D[q, d]: row = q0 + lg*4 + rr, col = dt*16 + lr; scale by rs_r here
#pragma unroll
        for (int dt = 0; dt < 8; ++dt)
#pragma unroll
            for (int rr = 0; rr < 4; ++rr) {
                int q = q0 + lg * 4 + rr;
                if (q < N_TOK) {
                    float v = acc[dt][rr] * rs_r[rr];
                    float hs = v * fminf(fmaxf(v + 3.f, 0.f), 6.f) * (1.f / 6.f);
                    attn_c[((size_t)bl * N_TOK + q) * 1536 + h * 128 + dt * 16 + lr] = (bf16)hs;
                }
            }
    }
}

// ---------------------------------------------------------------- proj GEMM
__global__ __launch_bounds__(256) void proj_gemm(
    const bf16* __restrict__ aio, const bf16* __restrict__ w,
    const float* __restrict__ sp, const float* __restrict__ bp,
    float* __restrict__ out)
{
    __shared__ bf16 As[128 * 40];
    __shared__ bf16 Bs[128 * 40];
    int t = threadIdx.x;
    int m0 = blockIdx.x * 128;
    int n0 = blockIdx.y * 128;
    int lane = t & 63, wid = t >> 6;
    int qr = (wid >> 1) * 64, qc = (wid & 1) * 64;
    int lr = lane & 15, lg = lane >> 4, lk = lg * 8;

    f32x4 acc[4][4];
#pragma unroll
    for (int fi = 0; fi < 4; ++fi)
#pragma unroll
        for (int fj = 0; fj < 4; ++fj)
            acc[fi][fj] = (f32x4){0.f, 0.f, 0.f, 0.f};

    int r = t >> 2, kk = (t & 3) * 8;
    for (int kt = 0; kt < 1536 / 32; ++kt) {
        int k0 = kt * 32;
        {
            *(bf16x8*)&As[r * 40 + kk] =
                *(const bf16x8*)(aio + (size_t)(m0 + r) * 1536 + k0 + kk);
            *(bf16x8*)&As[(r + 64) * 40 + kk] =
                *(const bf16x8*)(aio + (size_t)(m0 + r + 64) * 1536 + k0 + kk);
            *(bf16x8*)&Bs[r * 40 + kk] =
                *(const bf16x8*)(w + (size_t)(n0 + r) * 1536 + k0 + kk);
            *(bf16x8*)&Bs[(r + 64) * 40 + kk] =
                *(const bf16x8*)(w + (size_t)(n0 + r + 64) * 1536 + k0 + kk);
        }
        __syncthreads();
        bf16x8 a[4], b[4];
#pragma unroll
        for (int f = 0; f < 4; ++f) {
            a[f] = *(bf16x8*)&As[(qr + f * 16 + lr) * 40 + lk];
            b[f] = *(bf16x8*)&Bs[(qc + f * 16 + lr) * 40 + lk];
        }
#pragma unroll
        for (int fi = 0; fi < 4; ++fi)
#pragma unroll
            for (int fj = 0; fj < 4; ++fj)
                acc[fi][fj] = __builtin_amdgcn_mfma_f32_16x16x32_bf16(a[fi], b[fj], acc[fi][fj], 0, 0, 0);
        __syncthreads();
    }

#pragma unroll
    for (int fj = 0; fj < 4; ++fj) {
        int col = n0 + qc + fj * 16 + lr;
        float s = sp[col], bb = bp[col];
#pragma unroll
        for (int fi = 0; fi < 4; ++fi) {
            int rb = m0 + qr + fi * 16 + lg * 4;
#pragma unroll
            for (int rr = 0; rr < 4; ++rr) {
                int row = rb + rr;
                out[(size_t)row * DIM_ + col] = acc[fi][fj][rr] * s + bb;
            }
        }
    }
}

// ---------------------------------------------------------------- launch
extern "C" void kernel_launch(void* const* d_in, const int* in_sizes, int n_in,
                              void* d_out, int out_size, void* d_ws, size_t ws_size,
                              hipStream_t stream)
{
    const float* x          = (const float*)d_in[0];
    const float* qkv_w      = (const float*)d_in[1];
    const float* qkv_gamma  = (const float*)d_in[2];
    const float* qkv_beta   = (const float*)d_in[3];
    const float* qkv_mean   = (const float*)d_in[4];
    const float* qkv_var    = (const float*)d_in[5];
    const float* abias      = (const float*)d_in[6];
    const float* proj_w     = (const float*)d_in[7];
    const float* proj_gamma = (const float*)d_in[8];
    const float* proj_beta  = (const float*)d_in[9];
    const float* proj_mean  = (const float*)d_in[10];
    const float* proj_var   = (const float*)d_in[11];
    const int*   bias_idxs  = (const int*)d_in[12];
    float* out = (float*)d_out;

    char* wp = (char*)d_ws;
    auto alloc = [&](size_t bytes) {
        char* r = wp;
        wp += (bytes + 255) & ~(size_t)255;
        return r;
    };
    float* sqkv  = (float*)alloc((size_t)HQKV * 4);
    float* bqkv  = (float*)alloc((size_t)HQKV * 4);
    float* sproj = (float*)alloc((size_t)DIM_ * 4);
    float* bproj = (float*)alloc((size_t)DIM_ * 4);
    float* abT   = (float*)alloc((size_t)NH * NPAD * NPAD * 4);
    bf16* xb     = (bf16*)alloc((size_t)B_TOT * N_TOK * DIM_ * 2);
    bf16* wb     = (bf16*)alloc((size_t)HQKV * DIM_ * 2);
    bf16* pwb    = (bf16*)alloc((size_t)DIM_ * 1536 * 2);

    size_t fixed_used = (size_t)(wp - (char*)d_ws);
    auto per_chunk = [](int bc) {
        size_t q = ((size_t)bc * NH * NPAD * 192 * 2 + 255) & ~(size_t)255;
        size_t a = ((size_t)bc * N_TOK * 1536 * 2 + 255) & ~(size_t)255;
        return q + a;
    };
    int bchunk = 32;
    const int cands[4] = {256, 128, 64, 32};
    for (int ci = 0; ci < 4; ++ci) {
        if (fixed_used + per_chunk(cands[ci]) <= ws_size) { bchunk = cands[ci]; break; }
    }
    bf16* qkv_c  = (bf16*)alloc((size_t)bchunk * NH * NPAD * 192 * 2);
    bf16* attn_c = (bf16*)alloc((size_t)bchunk * N_TOK * 1536 * 2);

    int prep_grid = (NH * NPAD * NPAD + 255) / 256;
    prep_kernel<<<prep_grid, 256, 0, stream>>>(
        qkv_gamma, qkv_beta, qkv_mean, qkv_var,
        proj_gamma, proj_beta, proj_mean, proj_var,
        abias, bias_idxs, sqkv, bqkv, sproj, bproj, abT);

    convert_kernel<<<2048, 256, 0, stream>>>(x, xb, B_TOT * N_TOK * DIM_ / 4);
    convert_kernel<<<512, 256, 0, stream>>>(qkv_w, wb, HQKV * DIM_ / 4);
    convert_kernel<<<512, 256, 0, stream>>>(proj_w, pwb, DIM_ * 1536 / 4);

    int mrows = bchunk * N_TOK;
    for (int c = 0; c < B_TOT / bchunk; ++c) {
        const bf16* xc = xb + (size_t)c * bchunk * N_TOK * DIM_;
        float* oc = out + (size_t)c * bchunk * N_TOK * DIM_;
        qkv_gemm<<<dim3(mrows / 128, HQKV / 128), 256, 0, stream>>>(
            xc, wb, sqkv, bqkv, qkv_c);
        attn_kernel<<<dim3(bchunk * NH), 512, 0, stream>>>(qkv_c, abT, attn_c);
        proj_gemm<<<dim3(mrows / 128, DIM_ / 128), 256, 0, stream>>>(
            attn_c, pwb, sproj, bproj, oc);
    }
}

// Round 7
// 930.826 us; speedup vs baseline: 1.0611x; 1.0611x over previous
//
#include <hip/hip_runtime.h>
#include <hip/hip_bf16.h>
#include <cstdint>
#include <cstddef>

typedef __bf16 bf16;
typedef bf16 bf16x8 __attribute__((ext_vector_type(8)));
typedef float f32x4 __attribute__((ext_vector_type(4)));

#define N_TOK 196
#define DIM_ 384
#define HQKV 2304
#define NH 12
#define NPAD 224          // padded token count (m dim), 7*32
#define B_TOT 256

// ---------------------------------------------------------------- prep
__global__ __launch_bounds__(256) void prep_kernel(
    const float* __restrict__ qg, const float* __restrict__ qb,
    const float* __restrict__ qm, const float* __restrict__ qv,
    const float* __restrict__ pg, const float* __restrict__ pb,
    const float* __restrict__ pm, const float* __restrict__ pv,
    const float* __restrict__ abias, const int* __restrict__ idxs,
    float* __restrict__ sqkv, float* __restrict__ bqkv,
    float* __restrict__ sproj, float* __restrict__ bproj,
    float* __restrict__ ebT)
{
    int i = blockIdx.x * 256 + threadIdx.x;
    if (i < HQKV) {
        float s = qg[i] * rsqrtf(qv[i] + 1e-5f);
        sqkv[i] = s;
        bqkv[i] = qb[i] - qm[i] * s;
    }
    if (i < DIM_) {
        float s = pg[i] * rsqrtf(pv[i] + 1e-5f);
        sproj[i] = s;
        bproj[i] = pb[i] - pm[i] * s;
    }
    // ebT[h][m][q] = exp(bias[key m, query q]); 0 in padding -> exact mask
    if (i < NH * NPAD * NPAD) {
        int h = i / (NPAD * NPAD);
        int rem = i - h * (NPAD * NPAD);
        int m = rem / NPAD;
        int q = rem - m * NPAD;
        float v = 0.f;
        if (m < N_TOK && q < N_TOK)
            v = expf(abias[h * N_TOK + idxs[q * N_TOK + m]]);
        ebT[i] = v;
    }
}

// ---------------------------------------------------------------- f32 -> bf16 convert
__global__ __launch_bounds__(256) void convert_kernel(
    const float* __restrict__ src, bf16* __restrict__ dst, int n4)
{
    int stride = gridDim.x * 256;
    for (int i = blockIdx.x * 256 + threadIdx.x; i < n4; i += stride) {
        float4 v = ((const float4*)src)[i];
        bf16 o[4] = {(bf16)v.x, (bf16)v.y, (bf16)v.z, (bf16)v.w};
        *(uint2*)&dst[(size_t)i * 4] = *(uint2*)o;
    }
}

// ---------------------------------------------------------------- QKV GEMM (bf16 x bf16)
__global__ __launch_bounds__(256) void qkv_gemm(
    const bf16* __restrict__ x, const bf16* __restrict__ w,
    const float* __restrict__ sq, const float* __restrict__ bq,
    bf16* __restrict__ qkv_c)
{
    __shared__ bf16 As[128 * 40];
    __shared__ bf16 Bs[128 * 40];
    int t = threadIdx.x;
    int m0 = blockIdx.x * 128;
    int n0 = blockIdx.y * 128;
    int lane = t & 63, wid = t >> 6;
    int qr = (wid >> 1) * 64, qc = (wid & 1) * 64;
    int lr = lane & 15, lg = lane >> 4, lk = lg * 8;

    f32x4 acc[4][4];
#pragma unroll
    for (int fi = 0; fi < 4; ++fi)
#pragma unroll
        for (int fj = 0; fj < 4; ++fj)
            acc[fi][fj] = (f32x4){0.f, 0.f, 0.f, 0.f};

    int r = t >> 2, kk = (t & 3) * 8;
    for (int kt = 0; kt < DIM_ / 32; ++kt) {
        int k0 = kt * 32;
        {
            *(bf16x8*)&As[r * 40 + kk] =
                *(const bf16x8*)(x + (size_t)(m0 + r) * DIM_ + k0 + kk);
            *(bf16x8*)&As[(r + 64) * 40 + kk] =
                *(const bf16x8*)(x + (size_t)(m0 + r + 64) * DIM_ + k0 + kk);
            *(bf16x8*)&Bs[r * 40 + kk] =
                *(const bf16x8*)(w + (size_t)(n0 + r) * DIM_ + k0 + kk);
            *(bf16x8*)&Bs[(r + 64) * 40 + kk] =
                *(const bf16x8*)(w + (size_t)(n0 + r + 64) * DIM_ + k0 + kk);
        }
        __syncthreads();
        bf16x8 a[4], b[4];
#pragma unroll
        for (int f = 0; f < 4; ++f) {
            a[f] = *(bf16x8*)&As[(qr + f * 16 + lr) * 40 + lk];
            b[f] = *(bf16x8*)&Bs[(qc + f * 16 + lr) * 40 + lk];
        }
#pragma unroll
        for (int fi = 0; fi < 4; ++fi)
#pragma unroll
            for (int fj = 0; fj < 4; ++fj)
                acc[fi][fj] = __builtin_amdgcn_mfma_f32_16x16x32_bf16(a[fi], b[fj], acc[fi][fj], 0, 0, 0);
        __syncthreads();
    }

#pragma unroll
    for (int fj = 0; fj < 4; ++fj) {
        int col = n0 + qc + fj * 16 + lr;
        float s = sq[col], bb = bq[col];
        int h = col / 192, cc = col - h * 192;
#pragma unroll
        for (int fi = 0; fi < 4; ++fi) {
            int rb = m0 + qr + fi * 16 + lg * 4;
#pragma unroll
            for (int rr = 0; rr < 4; ++rr) {
                int row = rb + rr;
                int bl = row / N_TOK, n = row - bl * N_TOK;
                float v = acc[fi][fj][rr] * s + bb;
                qkv_c[((size_t)(bl * NH + h) * NPAD + n) * 192 + cc] = (bf16)v;
            }
        }
    }
}

// ---------------------------------------------------------------- attention
// qkv_c: [B*12][224][192] bf16 (cols 0:32 q, 32:64 k, 64:192 v)
// ebT: [12][224][224] f32 (exp(bias)[m][q], 0 in pads), attn_c: [B*196][1536]
// Two-pass scores: pass 1 computes only the running raw-score max (S never
// materializes as an array); pass 2 recomputes S per ks-pair and immediately
// exp+packs to bf16. softmax(S*scl+b) == normalize(exp2((S-mx)*scl*L2E)*e^b):
// row-constant mx cancels; e^b==0 masks padding exactly.
// R4/R6 lesson: S[14] f32 live across the pack phase blew the 128-VGPR cap
// (LDS 73.5KB -> 2 blk/CU -> 4 waves/SIMD) and spilled ~450MB/dispatch.
// R5 lesson: rs is per-lane for q=q0+lr; acc rows are q=q0+lg*4+rr -> shfl.
__global__ __launch_bounds__(512) void attn_kernel(
    const bf16* __restrict__ qkv_c, const float* __restrict__ ebT,
    bf16* __restrict__ attn_c)
{
    __shared__ bf16 k_s[224 * 40];
    __shared__ bf16 vT_s[128 * 224];   // [d][slot], XOR-swizzled
    int bh = blockIdx.x;
    int bl = bh / NH, h = bh - bl * NH;
    const bf16* base = qkv_c + (size_t)bh * NPAD * 192;
    int t = threadIdx.x;

    // stage K (rows >=196 zeroed)
    for (int c = t; c < 224 * 4; c += 512) {
        int r = c >> 2, g = c & 3;
        bf16x8 v;
        if (r < N_TOK) v = *(const bf16x8*)(base + (size_t)r * 192 + 32 + g * 8);
        else {
#pragma unroll
            for (int j = 0; j < 8; ++j) v[j] = (bf16)0.f;
        }
        *(bf16x8*)&k_s[r * 40 + g * 8] = v;
    }
    // stage V transposed: vT_s[d][slot(m)], slot permutation matches the
    // PV A-fragment k-order: slot = 32*blk + 8*g4 + 4*t16 + r4.
    for (int c = t; c < 56 * 16; c += 512) {
        int rp = c % 56, g = c / 56;
        int r0 = rp * 4;
        bf16x8 v[4];
#pragma unroll
        for (int i = 0; i < 4; ++i) {
            int rr = r0 + i;
            if (rr < N_TOK) v[i] = *(const bf16x8*)(base + (size_t)rr * 192 + 64 + g * 8);
            else {
#pragma unroll
                for (int j = 0; j < 8; ++j) v[i][j] = (bf16)0.f;
            }
        }
        int ml = r0 & 31, blk = r0 >> 5;
        int slot0 = blk * 32 + ((ml & 15) >> 2) * 8 + (ml >> 4) * 4 + (ml & 3);
#pragma unroll
        for (int j = 0; j < 8; ++j) {
            int d = g * 8 + j;
            bf16 w4[4] = {v[0][j], v[1][j], v[2][j], v[3][j]};
            int byte_off = (d * 448 + slot0 * 2) ^ ((d & 7) << 4);
            *(unsigned long long*)((char*)vT_s + byte_off) = *(unsigned long long*)w4;
        }
    }
    __syncthreads();

    int lane = t & 63, wid = t >> 6;
    int lr = lane & 15, lg = lane >> 4, lk = lg * 8;
    const float CSL = 0.17677669529663687f * 1.4426950408889634f; // scl*log2(e)
    const float* ebh = ebT + (size_t)h * NPAD * NPAD;
    int xorv = (lr & 7) << 4;
    const f32x4 z = (f32x4){0.f, 0.f, 0.f, 0.f};

    for (int tile = wid; tile < 13; tile += 8) {
        int q0 = tile * 16;
        // Q fragment (B operand): lane holds q = q0+lr, k contig
        bf16x8 aq = *(const bf16x8*)(base + (size_t)(q0 + lr) * 192 + lk);
        // ---- pass 1: raw-score max only (masked rows give 0; included, fine)
        float mxr = 0.f;
#pragma unroll
        for (int mt = 0; mt < 14; ++mt) {
            bf16x8 ak = *(const bf16x8*)&k_s[(mt * 16 + lr) * 40 + lk];
            f32x4 Sv = __builtin_amdgcn_mfma_f32_16x16x32_bf16(ak, aq, z, 0, 0, 0);
#pragma unroll
            for (int rr = 0; rr < 4; ++rr) mxr = fmaxf(mxr, Sv[rr]);
        }
        mxr = fmaxf(mxr, __shfl_xor(mxr, 16, 64));
        mxr = fmaxf(mxr, __shfl_xor(mxr, 32, 64));

        int qc = q0 + lr; if (qc > N_TOK - 1) qc = N_TOK - 1;
        // ---- pass 2: recompute S, exp, apply exp(bias), pack to bf16
        bf16x8 pa[7];
        float sum = 0.f;
#pragma unroll
        for (int ks = 0; ks < 7; ++ks) {
            bf16x8 ak0 = *(const bf16x8*)&k_s[((2 * ks) * 16 + lr) * 40 + lk];
            bf16x8 ak1 = *(const bf16x8*)&k_s[((2 * ks + 1) * 16 + lr) * 40 + lk];
            f32x4 S0 = __builtin_amdgcn_mfma_f32_16x16x32_bf16(ak0, aq, z, 0, 0, 0);
            f32x4 S1 = __builtin_amdgcn_mfma_f32_16x16x32_bf16(ak1, aq, z, 0, 0, 0);
#pragma unroll
            for (int e = 0; e < 4; ++e) {
                int m0_ = (2 * ks) * 16 + lg * 4 + e;
                int m1_ = (2 * ks + 1) * 16 + lg * 4 + e;
                float p0 = exp2f((S0[e] - mxr) * CSL) * ebh[(size_t)m0_ * NPAD + qc];
                float p1 = exp2f((S1[e] - mxr) * CSL) * ebh[(size_t)m1_ * NPAD + qc];
                sum += p0 + p1;
                pa[ks][e] = (bf16)p0;
                pa[ks][e + 4] = (bf16)p1;
            }
        }
        sum += __shfl_xor(sum, 16, 64);
        sum += __shfl_xor(sum, 32, 64);
        float rs = 1.f / sum;
        // acc rows are q = q0+lg*4+rr; their sums live in lanes lr==lg*4+rr
        float rs_r[4];
#pragma unroll
        for (int rr = 0; rr < 4; ++rr)
            rs_r[rr] = __shfl(rs, lg * 4 + rr, 64);

        f32x4 acc[8];
#pragma unroll
        for (int dt = 0; dt < 8; ++dt) acc[dt] = (f32x4){0.f, 0.f, 0.f, 0.f};
#pragma unroll
        for (int ks = 0; ks < 7; ++ks)
#pragma unroll
            for (int dt = 0; dt < 8; ++dt) {
                int byte_off = ((dt * 16 + lr) * 448 + ks * 64 + lg * 16) ^ xorv;
                bf16x8 bv = *(const bf16x8*)((const char*)vT_s + byte_off);
                acc[dt] = __builtin_amdgcn_mfma_f32_16x16x32_bf16(pa[ks], bv, acc[dt], 0, 0, 0);
            }
        // D[q, d]: row = q0 + lg*4 + rr, col = dt*16 + lr; scale by rs_r here
#pragma unroll
        for (int dt = 0; dt < 8; ++dt)
#pragma unroll
            for (int rr = 0; rr < 4; ++rr) {
                int q = q0 + lg * 4 + rr;
                if (q < N_TOK) {
                    float v = acc[dt][rr] * rs_r[rr];
                    float hs = v * fminf(fmaxf(v + 3.f, 0.f), 6.f) * (1.f / 6.f);
                    attn_c[((size_t)bl * N_TOK + q) * 1536 + h * 128 + dt * 16 + lr] = (bf16)hs;
                }
            }
    }
}

// ---------------------------------------------------------------- proj GEMM
__global__ __launch_bounds__(256) void proj_gemm(
    const bf16* __restrict__ aio, const bf16* __restrict__ w,
    const float* __restrict__ sp, const float* __restrict__ bp,
    float* __restrict__ out)
{
    __shared__ bf16 As[128 * 40];
    __shared__ bf16 Bs[128 * 40];
    int t = threadIdx.x;
    int m0 = blockIdx.x * 128;
    int n0 = blockIdx.y * 128;
    int lane = t & 63, wid = t >> 6;
    int qr = (wid >> 1) * 64, qc = (wid & 1) * 64;
    int lr = lane & 15, lg = lane >> 4, lk = lg * 8;

    f32x4 acc[4][4];
#pragma unroll
    for (int fi = 0; fi < 4; ++fi)
#pragma unroll
        for (int fj = 0; fj < 4; ++fj)
            acc[fi][fj] = (f32x4){0.f, 0.f, 0.f, 0.f};

    int r = t >> 2, kk = (t & 3) * 8;
    for (int kt = 0; kt < 1536 / 32; ++kt) {
        int k0 = kt * 32;
        {
            *(bf16x8*)&As[r * 40 + kk] =
                *(const bf16x8*)(aio + (size_t)(m0 + r) * 1536 + k0 + kk);
            *(bf16x8*)&As[(r + 64) * 40 + kk] =
                *(const bf16x8*)(aio + (size_t)(m0 + r + 64) * 1536 + k0 + kk);
            *(bf16x8*)&Bs[r * 40 + kk] =
                *(const bf16x8*)(w + (size_t)(n0 + r) * 1536 + k0 + kk);
            *(bf16x8*)&Bs[(r + 64) * 40 + kk] =
                *(const bf16x8*)(w + (size_t)(n0 + r + 64) * 1536 + k0 + kk);
        }
        __syncthreads();
        bf16x8 a[4], b[4];
#pragma unroll
        for (int f = 0; f < 4; ++f) {
            a[f] = *(bf16x8*)&As[(qr + f * 16 + lr) * 40 + lk];
            b[f] = *(bf16x8*)&Bs[(qc + f * 16 + lr) * 40 + lk];
        }
#pragma unroll
        for (int fi = 0; fi < 4; ++fi)
#pragma unroll
            for (int fj = 0; fj < 4; ++fj)
                acc[fi][fj] = __builtin_amdgcn_mfma_f32_16x16x32_bf16(a[fi], b[fj], acc[fi][fj], 0, 0, 0);
        __syncthreads();
    }

#pragma unroll
    for (int fj = 0; fj < 4; ++fj) {
        int col = n0 + qc + fj * 16 + lr;
        float s = sp[col], bb = bp[col];
#pragma unroll
        for (int fi = 0; fi < 4; ++fi) {
            int rb = m0 + qr + fi * 16 + lg * 4;
#pragma unroll
            for (int rr = 0; rr < 4; ++rr) {
                int row = rb + rr;
                out[(size_t)row * DIM_ + col] = acc[fi][fj][rr] * s + bb;
            }
        }
    }
}

// ---------------------------------------------------------------- launch
extern "C" void kernel_launch(void* const* d_in, const int* in_sizes, int n_in,
                              void* d_out, int out_size, void* d_ws, size_t ws_size,
                              hipStream_t stream)
{
    const float* x          = (const float*)d_in[0];
    const float* qkv_w      = (const float*)d_in[1];
    const float* qkv_gamma  = (const float*)d_in[2];
    const float* qkv_beta   = (const float*)d_in[3];
    const float* qkv_mean   = (const float*)d_in[4];
    const float* qkv_var    = (const float*)d_in[5];
    const float* abias      = (const float*)d_in[6];
    const float* proj_w     = (const float*)d_in[7];
    const float* proj_gamma = (const float*)d_in[8];
    const float* proj_beta  = (const float*)d_in[9];
    const float* proj_mean  = (const float*)d_in[10];
    const float* proj_var   = (const float*)d_in[11];
    const int*   bias_idxs  = (const int*)d_in[12];
    float* out = (float*)d_out;

    char* wp = (char*)d_ws;
    auto alloc = [&](size_t bytes) {
        char* r = wp;
        wp += (bytes + 255) & ~(size_t)255;
        return r;
    };
    float* sqkv  = (float*)alloc((size_t)HQKV * 4);
    float* bqkv  = (float*)alloc((size_t)HQKV * 4);
    float* sproj = (float*)alloc((size_t)DIM_ * 4);
    float* bproj = (float*)alloc((size_t)DIM_ * 4);
    float* ebT   = (float*)alloc((size_t)NH * NPAD * NPAD * 4);
    bf16* xb     = (bf16*)alloc((size_t)B_TOT * N_TOK * DIM_ * 2);
    bf16* wb     = (bf16*)alloc((size_t)HQKV * DIM_ * 2);
    bf16* pwb    = (bf16*)alloc((size_t)DIM_ * 1536 * 2);

    size_t fixed_used = (size_t)(wp - (char*)d_ws);
    auto per_chunk = [](int bc) {
        size_t q = ((size_t)bc * NH * NPAD * 192 * 2 + 255) & ~(size_t)255;
        size_t a = ((size_t)bc * N_TOK * 1536 * 2 + 255) & ~(size_t)255;
        return q + a;
    };
    int bchunk = 32;
    const int cands[4] = {256, 128, 64, 32};
    for (int ci = 0; ci < 4; ++ci) {
        if (fixed_used + per_chunk(cands[ci]) <= ws_size) { bchunk = cands[ci]; break; }
    }
    bf16* qkv_c  = (bf16*)alloc((size_t)bchunk * NH * NPAD * 192 * 2);
    bf16* attn_c = (bf16*)alloc((size_t)bchunk * N_TOK * 1536 * 2);

    int prep_grid = (NH * NPAD * NPAD + 255) / 256;
    prep_kernel<<<prep_grid, 256, 0, stream>>>(
        qkv_gamma, qkv_beta, qkv_mean, qkv_var,
        proj_gamma, proj_beta, proj_mean, proj_var,
        abias, bias_idxs, sqkv, bqkv, sproj, bproj, ebT);

    convert_kernel<<<2048, 256, 0, stream>>>(x, xb, B_TOT * N_TOK * DIM_ / 4);
    convert_kernel<<<512, 256, 0, stream>>>(qkv_w, wb, HQKV * DIM_ / 4);
    convert_kernel<<<512, 256, 0, stream>>>(proj_w, pwb, DIM_ * 1536 / 4);

    int mrows = bchunk * N_TOK;
    for (int c = 0; c < B_TOT / bchunk; ++c) {
        const bf16* xc = xb + (size_t)c * bchunk * N_TOK * DIM_;
        float* oc = out + (size_t)c * bchunk * N_TOK * DIM_;
        qkv_gemm<<<dim3(mrows / 128, HQKV / 128), 256, 0, stream>>>(
            xc, wb, sqkv, bqkv, qkv_c);
        attn_kernel<<<dim3(bchunk * NH), 512, 0, stream>>>(qkv_c, ebT, attn_c);
        proj_gemm<<<dim3(mrows / 128, DIM_ / 128), 256, 0, stream>>>(
            attn_c, pwb, sproj, bproj, oc);
    }
}

// Round 8
// 927.765 us; speedup vs baseline: 1.0646x; 1.0033x over previous
//
#include <hip/hip_runtime.h>
#include <hip/hip_bf16.h>
#include <cstdint>
#include <cstddef>

typedef __bf16 bf16;
typedef bf16 bf16x8 __attribute__((ext_vector_type(8)));
typedef float f32x4 __attribute__((ext_vector_type(4)));

#define N_TOK 196
#define DIM_ 384
#define HQKV 2304
#define NH 12
#define NPAD 224          // padded token count (m dim), 7*32
#define B_TOT 256

// ---------------------------------------------------------------- prep
__global__ __launch_bounds__(256) void prep_kernel(
    const float* __restrict__ qg, const float* __restrict__ qb,
    const float* __restrict__ qm, const float* __restrict__ qv,
    const float* __restrict__ pg, const float* __restrict__ pb,
    const float* __restrict__ pm, const float* __restrict__ pv,
    const float* __restrict__ abias, const int* __restrict__ idxs,
    float* __restrict__ sqkv, float* __restrict__ bqkv,
    float* __restrict__ sproj, float* __restrict__ bproj,
    float* __restrict__ ebT)
{
    int i = blockIdx.x * 256 + threadIdx.x;
    if (i < HQKV) {
        float s = qg[i] * rsqrtf(qv[i] + 1e-5f);
        sqkv[i] = s;
        bqkv[i] = qb[i] - qm[i] * s;
    }
    if (i < DIM_) {
        float s = pg[i] * rsqrtf(pv[i] + 1e-5f);
        sproj[i] = s;
        bproj[i] = pb[i] - pm[i] * s;
    }
    // ebT[h][m][q] = exp(bias[key m, query q]); 0 in padding -> exact mask
    if (i < NH * NPAD * NPAD) {
        int h = i / (NPAD * NPAD);
        int rem = i - h * (NPAD * NPAD);
        int m = rem / NPAD;
        int q = rem - m * NPAD;
        float v = 0.f;
        if (m < N_TOK && q < N_TOK)
            v = expf(abias[h * N_TOK + idxs[q * N_TOK + m]]);
        ebT[i] = v;
    }
}

// ---------------------------------------------------------------- f32 -> bf16 convert
__global__ __launch_bounds__(256) void convert_kernel(
    const float* __restrict__ src, bf16* __restrict__ dst, int n4)
{
    int stride = gridDim.x * 256;
    for (int i = blockIdx.x * 256 + threadIdx.x; i < n4; i += stride) {
        float4 v = ((const float4*)src)[i];
        bf16 o[4] = {(bf16)v.x, (bf16)v.y, (bf16)v.z, (bf16)v.w};
        *(uint2*)&dst[(size_t)i * 4] = *(uint2*)o;
    }
}

// ---------------------------------------------------------------- QKV GEMM (bf16 x bf16)
__global__ __launch_bounds__(256) void qkv_gemm(
    const bf16* __restrict__ x, const bf16* __restrict__ w,
    const float* __restrict__ sq, const float* __restrict__ bq,
    bf16* __restrict__ qkv_c)
{
    __shared__ bf16 As[128 * 40];
    __shared__ bf16 Bs[128 * 40];
    int t = threadIdx.x;
    int m0 = blockIdx.x * 128;
    int n0 = blockIdx.y * 128;
    int lane = t & 63, wid = t >> 6;
    int qr = (wid >> 1) * 64, qc = (wid & 1) * 64;
    int lr = lane & 15, lg = lane >> 4, lk = lg * 8;

    f32x4 acc[4][4];
#pragma unroll
    for (int fi = 0; fi < 4; ++fi)
#pragma unroll
        for (int fj = 0; fj < 4; ++fj)
            acc[fi][fj] = (f32x4){0.f, 0.f, 0.f, 0.f};

    int r = t >> 2, kk = (t & 3) * 8;
    for (int kt = 0; kt < DIM_ / 32; ++kt) {
        int k0 = kt * 32;
        {
            *(bf16x8*)&As[r * 40 + kk] =
                *(const bf16x8*)(x + (size_t)(m0 + r) * DIM_ + k0 + kk);
            *(bf16x8*)&As[(r + 64) * 40 + kk] =
                *(const bf16x8*)(x + (size_t)(m0 + r + 64) * DIM_ + k0 + kk);
            *(bf16x8*)&Bs[r * 40 + kk] =
                *(const bf16x8*)(w + (size_t)(n0 + r) * DIM_ + k0 + kk);
            *(bf16x8*)&Bs[(r + 64) * 40 + kk] =
                *(const bf16x8*)(w + (size_t)(n0 + r + 64) * DIM_ + k0 + kk);
        }
        __syncthreads();
        bf16x8 a[4], b[4];
#pragma unroll
        for (int f = 0; f < 4; ++f) {
            a[f] = *(bf16x8*)&As[(qr + f * 16 + lr) * 40 + lk];
            b[f] = *(bf16x8*)&Bs[(qc + f * 16 + lr) * 40 + lk];
        }
#pragma unroll
        for (int fi = 0; fi < 4; ++fi)
#pragma unroll
            for (int fj = 0; fj < 4; ++fj)
                acc[fi][fj] = __builtin_amdgcn_mfma_f32_16x16x32_bf16(a[fi], b[fj], acc[fi][fj], 0, 0, 0);
        __syncthreads();
    }

#pragma unroll
    for (int fj = 0; fj < 4; ++fj) {
        int col = n0 + qc + fj * 16 + lr;
        float s = sq[col], bb = bq[col];
        int h = col / 192, cc = col - h * 192;
#pragma unroll
        for (int fi = 0; fi < 4; ++fi) {
            int rb = m0 + qr + fi * 16 + lg * 4;
#pragma unroll
            for (int rr = 0; rr < 4; ++rr) {
                int row = rb + rr;
                int bl = row / N_TOK, n = row - bl * N_TOK;
                float v = acc[fi][fj][rr] * s + bb;
                qkv_c[((size_t)(bl * NH + h) * NPAD + n) * 192 + cc] = (bf16)v;
            }
        }
    }
}

// ---------------------------------------------------------------- attention
// qkv_c: [B*12][224][192] bf16 (cols 0:32 q, 32:64 k, 64:192 v)
// ebT: [12][224][224] f32 (exp(bias)[m][q], 0 in pads), attn_c: [B*196][1536]
// Two-pass scores; P packed to bf16 at exp time; 1/sum deferred (shfl'd to
// C-frag rows). __launch_bounds__(512, 2): LDS=73.5KB would allow 2 blk/CU,
// and with plain bounds the compiler CAPS VGPR at 128 to reach that
// occupancy, spilling ~580MB/dispatch to scratch (R4/R6/R7 all VGPR==128
// with 300-450MB extra fetch+write). Requesting 2 waves/SIMD raises the cap
// to 256 -> ~150-200 VGPR, zero spill, 1 blk/CU. R2 proved 1 blk/CU runs
// this shape in 114us even with a worse inner structure.
__global__ __launch_bounds__(512, 2) void attn_kernel(
    const bf16* __restrict__ qkv_c, const float* __restrict__ ebT,
    bf16* __restrict__ attn_c)
{
    __shared__ bf16 k_s[224 * 40];
    __shared__ bf16 vT_s[128 * 224];   // [d][slot], XOR-swizzled
    int bh = blockIdx.x;
    int bl = bh / NH, h = bh - bl * NH;
    const bf16* base = qkv_c + (size_t)bh * NPAD * 192;
    int t = threadIdx.x;

    // stage K (rows >=196 zeroed)
    for (int c = t; c < 224 * 4; c += 512) {
        int r = c >> 2, g = c & 3;
        bf16x8 v;
        if (r < N_TOK) v = *(const bf16x8*)(base + (size_t)r * 192 + 32 + g * 8);
        else {
#pragma unroll
            for (int j = 0; j < 8; ++j) v[j] = (bf16)0.f;
        }
        *(bf16x8*)&k_s[r * 40 + g * 8] = v;
    }
    // stage V transposed: vT_s[d][slot(m)], slot permutation matches the
    // PV A-fragment k-order: slot = 32*blk + 8*g4 + 4*t16 + r4.
    for (int c = t; c < 56 * 16; c += 512) {
        int rp = c % 56, g = c / 56;
        int r0 = rp * 4;
        bf16x8 v[4];
#pragma unroll
        for (int i = 0; i < 4; ++i) {
            int rr = r0 + i;
            if (rr < N_TOK) v[i] = *(const bf16x8*)(base + (size_t)rr * 192 + 64 + g * 8);
            else {
#pragma unroll
                for (int j = 0; j < 8; ++j) v[i][j] = (bf16)0.f;
            }
        }
        int ml = r0 & 31, blk = r0 >> 5;
        int slot0 = blk * 32 + ((ml & 15) >> 2) * 8 + (ml >> 4) * 4 + (ml & 3);
#pragma unroll
        for (int j = 0; j < 8; ++j) {
            int d = g * 8 + j;
            bf16 w4[4] = {v[0][j], v[1][j], v[2][j], v[3][j]};
            int byte_off = (d * 448 + slot0 * 2) ^ ((d & 7) << 4);
            *(unsigned long long*)((char*)vT_s + byte_off) = *(unsigned long long*)w4;
        }
    }
    __syncthreads();

    int lane = t & 63, wid = t >> 6;
    int lr = lane & 15, lg = lane >> 4, lk = lg * 8;
    const float CSL = 0.17677669529663687f * 1.4426950408889634f; // scl*log2(e)
    const float* ebh = ebT + (size_t)h * NPAD * NPAD;
    int xorv = (lr & 7) << 4;
    const f32x4 z = (f32x4){0.f, 0.f, 0.f, 0.f};

    for (int tile = wid; tile < 13; tile += 8) {
        int q0 = tile * 16;
        // Q fragment (B operand): lane holds q = q0+lr, k contig
        bf16x8 aq = *(const bf16x8*)(base + (size_t)(q0 + lr) * 192 + lk);
        // ---- pass 1: raw-score max only
        float mxr = 0.f;
#pragma unroll
        for (int mt = 0; mt < 14; ++mt) {
            bf16x8 ak = *(const bf16x8*)&k_s[(mt * 16 + lr) * 40 + lk];
            f32x4 Sv = __builtin_amdgcn_mfma_f32_16x16x32_bf16(ak, aq, z, 0, 0, 0);
#pragma unroll
            for (int rr = 0; rr < 4; ++rr) mxr = fmaxf(mxr, Sv[rr]);
        }
        mxr = fmaxf(mxr, __shfl_xor(mxr, 16, 64));
        mxr = fmaxf(mxr, __shfl_xor(mxr, 32, 64));

        int qc = q0 + lr; if (qc > N_TOK - 1) qc = N_TOK - 1;
        // ---- pass 2: recompute S, exp, apply exp(bias), pack to bf16
        bf16x8 pa[7];
        float sum = 0.f;
#pragma unroll
        for (int ks = 0; ks < 7; ++ks) {
            bf16x8 ak0 = *(const bf16x8*)&k_s[((2 * ks) * 16 + lr) * 40 + lk];
            bf16x8 ak1 = *(const bf16x8*)&k_s[((2 * ks + 1) * 16 + lr) * 40 + lk];
            f32x4 S0 = __builtin_amdgcn_mfma_f32_16x16x32_bf16(ak0, aq, z, 0, 0, 0);
            f32x4 S1 = __builtin_amdgcn_mfma_f32_16x16x32_bf16(ak1, aq, z, 0, 0, 0);
#pragma unroll
            for (int e = 0; e < 4; ++e) {
                int m0_ = (2 * ks) * 16 + lg * 4 + e;
                int m1_ = (2 * ks + 1) * 16 + lg * 4 + e;
                float p0 = exp2f((S0[e] - mxr) * CSL) * ebh[(size_t)m0_ * NPAD + qc];
                float p1 = exp2f((S1[e] - mxr) * CSL) * ebh[(size_t)m1_ * NPAD + qc];
                sum += p0 + p1;
                pa[ks][e] = (bf16)p0;
                pa[ks][e + 4] = (bf16)p1;
            }
        }
        sum += __shfl_xor(sum, 16, 64);
        sum += __shfl_xor(sum, 32, 64);
        float rs = 1.f / sum;
        // acc rows are q = q0+lg*4+rr; their sums live in lanes lr==lg*4+rr
        float rs_r[4];
#pragma unroll
        for (int rr = 0; rr < 4; ++rr)
            rs_r[rr] = __shfl(rs, lg * 4 + rr, 64);

        f32x4 acc[8];
#pragma unroll
        for (int dt = 0; dt < 8; ++dt) acc[dt] = (f32x4){0.f, 0.f, 0.f, 0.f};
#pragma unroll
        for (int ks = 0; ks < 7; ++ks)
#pragma unroll
            for (int dt = 0; dt < 8; ++dt) {
                int byte_off = ((dt * 16 + lr) * 448 + ks * 64 + lg * 16) ^ xorv;
                bf16x8 bv = *(const bf16x8*)((const char*)vT_s + byte_off);
                acc[dt] = __builtin_amdgcn_mfma_f32_16x16x32_bf16(pa[ks], bv, acc[dt], 0, 0, 0);
            }
        // D[q, d]: row = q0 + lg*4 + rr, col = dt*16 + lr; scale by rs_r here
#pragma unroll
        for (int dt = 0; dt < 8; ++dt)
#pragma unroll
            for (int rr = 0; rr < 4; ++rr) {
                int q = q0 + lg * 4 + rr;
                if (q < N_TOK) {
                    float v = acc[dt][rr] * rs_r[rr];
                    float hs = v * fminf(fmaxf(v + 3.f, 0.f), 6.f) * (1.f / 6.f);
                    attn_c[((size_t)bl * N_TOK + q) * 1536 + h * 128 + dt * 16 + lr] = (bf16)hs;
                }
            }
    }
}

// ---------------------------------------------------------------- proj GEMM
__global__ __launch_bounds__(256) void proj_gemm(
    const bf16* __restrict__ aio, const bf16* __restrict__ w,
    const float* __restrict__ sp, const float* __restrict__ bp,
    float* __restrict__ out)
{
    __shared__ bf16 As[128 * 40];
    __shared__ bf16 Bs[128 * 40];
    int t = threadIdx.x;
    int m0 = blockIdx.x * 128;
    int n0 = blockIdx.y * 128;
    int lane = t & 63, wid = t >> 6;
    int qr = (wid >> 1) * 64, qc = (wid & 1) * 64;
    int lr = lane & 15, lg = lane >> 4, lk = lg * 8;

    f32x4 acc[4][4];
#pragma unroll
    for (int fi = 0; fi < 4; ++fi)
#pragma unroll
        for (int fj = 0; fj < 4; ++fj)
            acc[fi][fj] = (f32x4){0.f, 0.f, 0.f, 0.f};

    int r = t >> 2, kk = (t & 3) * 8;
    for (int kt = 0; kt < 1536 / 32; ++kt) {
        int k0 = kt * 32;
        {
            *(bf16x8*)&As[r * 40 + kk] =
                *(const bf16x8*)(aio + (size_t)(m0 + r) * 1536 + k0 + kk);
            *(bf16x8*)&As[(r + 64) * 40 + kk] =
                *(const bf16x8*)(aio + (size_t)(m0 + r + 64) * 1536 + k0 + kk);
            *(bf16x8*)&Bs[r * 40 + kk] =
                *(const bf16x8*)(w + (size_t)(n0 + r) * 1536 + k0 + kk);
            *(bf16x8*)&Bs[(r + 64) * 40 + kk] =
                *(const bf16x8*)(w + (size_t)(n0 + r + 64) * 1536 + k0 + kk);
        }
        __syncthreads();
        bf16x8 a[4], b[4];
#pragma unroll
        for (int f = 0; f < 4; ++f) {
            a[f] = *(bf16x8*)&As[(qr + f * 16 + lr) * 40 + lk];
            b[f] = *(bf16x8*)&Bs[(qc + f * 16 + lr) * 40 + lk];
        }
#pragma unroll
        for (int fi = 0; fi < 4; ++fi)
#pragma unroll
            for (int fj = 0; fj < 4; ++fj)
                acc[fi][fj] = __builtin_amdgcn_mfma_f32_16x16x32_bf16(a[fi], b[fj], acc[fi][fj], 0, 0, 0);
        __syncthreads();
    }

#pragma unroll
    for (int fj = 0; fj < 4; ++fj) {
        int col = n0 + qc + fj * 16 + lr;
        float s = sp[col], bb = bp[col];
#pragma unroll
        for (int fi = 0; fi < 4; ++fi) {
            int rb = m0 + qr + fi * 16 + lg * 4;
#pragma unroll
            for (int rr = 0; rr < 4; ++rr) {
                int row = rb + rr;
                out[(size_t)row * DIM_ + col] = acc[fi][fj][rr] * s + bb;
            }
        }
    }
}

// ---------------------------------------------------------------- launch
extern "C" void kernel_launch(void* const* d_in, const int* in_sizes, int n_in,
                              void* d_out, int out_size, void* d_ws, size_t ws_size,
                              hipStream_t stream)
{
    const float* x          = (const float*)d_in[0];
    const float* qkv_w      = (const float*)d_in[1];
    const float* qkv_gamma  = (const float*)d_in[2];
    const float* qkv_beta   = (const float*)d_in[3];
    const float* qkv_mean   = (const float*)d_in[4];
    const float* qkv_var    = (const float*)d_in[5];
    const float* abias      = (const float*)d_in[6];
    const float* proj_w     = (const float*)d_in[7];
    const float* proj_gamma = (const float*)d_in[8];
    const float* proj_beta  = (const float*)d_in[9];
    const float* proj_mean  = (const float*)d_in[10];
    const float* proj_var   = (const float*)d_in[11];
    const int*   bias_idxs  = (const int*)d_in[12];
    float* out = (float*)d_out;

    char* wp = (char*)d_ws;
    auto alloc = [&](size_t bytes) {
        char* r = wp;
        wp += (bytes + 255) & ~(size_t)255;
        return r;
    };
    float* sqkv  = (float*)alloc((size_t)HQKV * 4);
    float* bqkv  = (float*)alloc((size_t)HQKV * 4);
    float* sproj = (float*)alloc((size_t)DIM_ * 4);
    float* bproj = (float*)alloc((size_t)DIM_ * 4);
    float* ebT   = (float*)alloc((size_t)NH * NPAD * NPAD * 4);
    bf16* xb     = (bf16*)alloc((size_t)B_TOT * N_TOK * DIM_ * 2);
    bf16* wb     = (bf16*)alloc((size_t)HQKV * DIM_ * 2);
    bf16* pwb    = (bf16*)alloc((size_t)DIM_ * 1536 * 2);

    size_t fixed_used = (size_t)(wp - (char*)d_ws);
    auto per_chunk = [](int bc) {
        size_t q = ((size_t)bc * NH * NPAD * 192 * 2 + 255) & ~(size_t)255;
        size_t a = ((size_t)bc * N_TOK * 1536 * 2 + 255) & ~(size_t)255;
        return q + a;
    };
    int bchunk = 32;
    const int cands[4] = {256, 128, 64, 32};
    for (int ci = 0; ci < 4; ++ci) {
        if (fixed_used + per_chunk(cands[ci]) <= ws_size) { bchunk = cands[ci]; break; }
    }
    bf16* qkv_c  = (bf16*)alloc((size_t)bchunk * NH * NPAD * 192 * 2);
    bf16* attn_c = (bf16*)alloc((size_t)bchunk * N_TOK * 1536 * 2);

    int prep_grid = (NH * NPAD * NPAD + 255) / 256;
    prep_kernel<<<prep_grid, 256, 0, stream>>>(
        qkv_gamma, qkv_beta, qkv_mean, qkv_var,
        proj_gamma, proj_beta, proj_mean, proj_var,
        abias, bias_idxs, sqkv, bqkv, sproj, bproj, ebT);

    convert_kernel<<<2048, 256, 0, stream>>>(x, xb, B_TOT * N_TOK * DIM_ / 4);
    convert_kernel<<<512, 256, 0, stream>>>(qkv_w, wb, HQKV * DIM_ / 4);
    convert_kernel<<<512, 256, 0, stream>>>(proj_w, pwb, DIM_ * 1536 / 4);

    int mrows = bchunk * N_TOK;
    for (int c = 0; c < B_TOT / bchunk; ++c) {
        const bf16* xc = xb + (size_t)c * bchunk * N_TOK * DIM_;
        float* oc = out + (size_t)c * bchunk * N_TOK * DIM_;
        qkv_gemm<<<dim3(mrows / 128, HQKV / 128), 256, 0, stream>>>(
            xc, wb, sqkv, bqkv, qkv_c);
        attn_kernel<<<dim3(bchunk * NH), 512, 0, stream>>>(qkv_c, ebT, attn_c);
        proj_gemm<<<dim3(mrows / 128, DIM_ / 128), 256, 0, stream>>>(
            attn_c, pwb, sproj, bproj, oc);
    }
}